// Round 2
// baseline (236.971 us; speedup 1.0000x reference)
//
#include <hip/hip_runtime.h>
#include <stdint.h>

// Problem constants: B=1, N=4096, C=256, H=8, D=64, H*D=512
#define NN 4096
#define CC 256
#define HD 512
#define DD 64
#define KSPLIT 3               // 64 k-tiles split 21/21/22 -> grid 768 = 3 blocks/CU exactly

typedef __attribute__((ext_vector_type(8))) short short8;
typedef __attribute__((ext_vector_type(4))) float floatx4;

__device__ __forceinline__ unsigned short f2bf(float x) {
    union { float f; unsigned int u; } v; v.f = x;
    unsigned int u = v.u + 0x7fffu + ((v.u >> 16) & 1u);
    return (unsigned short)(u >> 16);
}
__device__ __forceinline__ float bf2f(unsigned short s) {
    union { unsigned int u; float f; } v; v.u = ((unsigned int)s) << 16;
    return v.f;
}

// Pack two f32 -> bf16x2 (lo = first arg), RNE. HW instr on gfx950.
#if defined(__has_builtin) && __has_builtin(__builtin_amdgcn_cvt_pk_bf16_f32)
typedef __attribute__((ext_vector_type(2))) __bf16 bf16x2_t;
__device__ __forceinline__ unsigned int pack2bf(float a, float b) {
    union { bf16x2_t v; unsigned int u; } x;
    x.v = __builtin_amdgcn_cvt_pk_bf16_f32(a, b);
    return x.u;
}
#else
__device__ __forceinline__ unsigned int pack2bf(float a, float b) {
    return ((unsigned int)f2bf(b) << 16) | (unsigned int)f2bf(a);
}
#endif

// Async global->LDS, 16 B per lane; LDS dest = wave-uniform base + lane*16.
#define GLOAD_LDS(gp, lp) __builtin_amdgcn_global_load_lds(                    \
    (__attribute__((address_space(1))) void*)(gp),                             \
    (__attribute__((address_space(3))) void*)(lp), 16, 0, 0)

// ---------------------------------------------------------------------------
// Kernel 0: fp32 -> bf16 prep. z selects region. wq pre-scaled by 0.125.
// ---------------------------------------------------------------------------
__global__ __launch_bounds__(256) void prep_kernel(
    const float* __restrict__ qx, const float* __restrict__ kx,
    const float* __restrict__ vx,
    const float* __restrict__ wq, const float* __restrict__ wk,
    const float* __restrict__ wv, const float* __restrict__ wg,
    const float* __restrict__ wo,
    unsigned short* __restrict__ qxb, unsigned short* __restrict__ kxb,
    unsigned short* __restrict__ vxb, unsigned short* __restrict__ Wb,
    unsigned short* __restrict__ wob)
{
    const int z = blockIdx.y;
    const float* src; unsigned short* dst; int n; float s = 1.0f;
    switch (z) {
        case 0: src = qx; dst = qxb; n = NN * CC; break;
        case 1: src = kx; dst = kxb; n = NN * CC; break;
        case 2: src = vx; dst = vxb; n = NN * CC; break;
        case 3: src = wq; dst = Wb;               n = HD * CC; s = 0.125f; break;
        case 4: src = wk; dst = Wb + 1 * HD * CC; n = HD * CC; break;
        case 5: src = wv; dst = Wb + 2 * HD * CC; n = HD * CC; break;
        case 6: src = wg; dst = Wb + 3 * HD * CC; n = HD * CC; break;
        default: src = wo; dst = wob;             n = CC * HD; break;
    }
    int i = (blockIdx.x * 256 + threadIdx.x) * 4;
    if (i < n) {
        float4 v = *(const float4*)&src[i];
        ushort4 p;
        p.x = f2bf(v.x * s); p.y = f2bf(v.y * s);
        p.z = f2bf(v.z * s); p.w = f2bf(v.w * s);
        *(ushort4*)&dst[i] = p;
    }
}

// ---------------------------------------------------------------------------
// Kernel 1: fused projection GEMM. X[4096][256]bf16 @ Wb[2048][256]^T.
// Tile 128x128, BK=64. Staging via global_load_lds (16B/lane) into UNPADDED
// rows (64 shorts = 128 B) with XOR chunk swizzle: LDS slot j of row r holds
// source 8-short chunk j^(r&7); reads XOR the same way -> conflict-free.
// ---------------------------------------------------------------------------
__global__ __launch_bounds__(256, 4) void proj_kernel(
    const unsigned short* __restrict__ qxb, const unsigned short* __restrict__ kxb,
    const unsigned short* __restrict__ vxb, const unsigned short* __restrict__ Wb,
    const float* __restrict__ bg,
    unsigned short* __restrict__ Qb, unsigned short* __restrict__ Kb,
    unsigned short* __restrict__ VbT, unsigned short* __restrict__ Gb)
{
    const int m0 = blockIdx.x * 128;
    const int nb = blockIdx.y;
    const int n0 = nb * 128;
    const int mode = nb >> 2;
    const unsigned short* X = (mode == 1) ? kxb : (mode == 2) ? vxb : qxb;

    const int tid = threadIdx.x;
    const int wid = tid >> 6;
    const int wr = wid >> 1, wc = wid & 1;
    const int lane = tid & 63;
    const int quad = lane >> 4;
    const int ln = lane & 15;
    const int lnx = ln & 7;

    // Xs: 128x64 @ smem[0], Ws: 128x64 @ smem[8192]; transpose scratch reuses
    // the whole buffer (128x136 = 17408 shorts) after the final barrier.
    __shared__ __align__(16) unsigned short smem[128 * 136];
    unsigned short* Xs = smem;
    unsigned short* Ws = smem + 128 * 64;

    floatx4 acc[4][4] = {};

    for (int k0 = 0; k0 < CC; k0 += 64) {
        #pragma unroll
        for (int t = 0; t < 4; t++) {
            int row = wid * 32 + t * 8 + (lane >> 3);
            int c = (lane & 7) ^ (lane >> 3);
            GLOAD_LDS(&X[(size_t)(m0 + row) * CC + k0 + c * 8],
                      &Xs[(wid * 32 + t * 8) * 64]);
            GLOAD_LDS(&Wb[(size_t)(n0 + row) * CC + k0 + c * 8],
                      &Ws[(wid * 32 + t * 8) * 64]);
        }
        __syncthreads();

        #pragma unroll
        for (int ks = 0; ks < 64; ks += 32) {
            const int cb = ks >> 3;    // 0 or 4
            short8 a[4], b[4];
            #pragma unroll
            for (int i = 0; i < 4; i++)
                a[i] = *(const short8*)&Xs[(wr * 64 + i * 16 + ln) * 64 +
                                           (((quad ^ cb) ^ lnx) * 8)];
            #pragma unroll
            for (int j = 0; j < 4; j++)
                b[j] = *(const short8*)&Ws[(wc * 64 + j * 16 + ln) * 64 +
                                           (((quad ^ cb) ^ lnx) * 8)];
            #pragma unroll
            for (int i = 0; i < 4; i++)
                #pragma unroll
                for (int j = 0; j < 4; j++)
                    acc[i][j] = __builtin_amdgcn_mfma_f32_16x16x32_bf16(a[i], b[j], acc[i][j], 0, 0, 0);
        }
        __syncthreads();
    }

    const int subn = nb & 3;
    if (mode != 2) {
        unsigned short* Out = (mode == 0) ? Qb : (mode == 1) ? Kb : Gb;
        #pragma unroll
        for (int i = 0; i < 4; i++) {
            #pragma unroll
            for (int j = 0; j < 4; j++) {
                int col = subn * 128 + wc * 64 + j * 16 + ln;
                float bgv = (mode == 3) ? bg[col] : 0.0f;
                #pragma unroll
                for (int r = 0; r < 4; r++) {
                    int row = m0 + wr * 64 + i * 16 + quad * 4 + r;
                    float v = acc[i][j][r];
                    if (mode == 3) v = 1.0f / (1.0f + __expf(-(v + bgv)));
                    Out[(size_t)row * HD + col] = f2bf(v);
                }
            }
        }
    } else {
        // V: transpose through smem, store coalesced to VbT[col][row]
        #pragma unroll
        for (int i = 0; i < 4; i++) {
            #pragma unroll
            for (int j = 0; j < 4; j++) {
                int cl = wc * 64 + j * 16 + ln;
                #pragma unroll
                for (int r = 0; r < 4; r++) {
                    int rl = wr * 64 + i * 16 + quad * 4 + r;
                    smem[cl * 136 + rl] = f2bf(acc[i][j][r]);
                }
            }
        }
        __syncthreads();
        #pragma unroll
        for (int it = 0; it < 8; it++) {
            int idx = it * 256 + tid;
            int c = idx >> 4, ch = idx & 15;
            short8 vv = *(const short8*)&smem[c * 136 + ch * 8];
            *(short8*)&VbT[(size_t)(subn * 128 + c) * NN + m0 + ch * 8] = vv;
        }
    }
}

// ---------------------------------------------------------------------------
// Kernel 2: flash attention. Q-tile 128/block, each wave owns 32 q-rows
// (m-repeat=2): every K/V fragment read from LDS feeds 2 MFMAs -> LDS read
// traffic per unit work drops 44% vs the 16-row layout (the round-1 counters
// showed the kernel is LDS-pipe-bound: MfmaUtil 17%, VALU 34%, HBM 15%).
// K/V double-buffered (prefetch at top, single barrier at bottom); bias for
// tile t+1 is loaded directly into the S accumulator registers after softmax
// consumes S (bias = MFMA C-init), so no separate bias registers exist.
// LDS = Ks 16 + Vs 16 + Ps 16 = 48 KB -> 3 blocks/CU; grid 768 = 3/CU exact.
// ---------------------------------------------------------------------------
__global__ __launch_bounds__(256, 3) void attn_kernel(
    const unsigned short* __restrict__ Qb, const unsigned short* __restrict__ Kb,
    const unsigned short* __restrict__ VbT,
    const float* __restrict__ bias,
    unsigned short* __restrict__ Opart, float* __restrict__ Lpart)
{
    const int h = blockIdx.y;
    const int q0 = blockIdx.x * 128;
    const int sp = blockIdx.z;
    const int tbeg = (sp * 64) / KSPLIT;
    const int tend = ((sp + 1) * 64) / KSPLIT;
    const int tid = threadIdx.x;
    const int wid = tid >> 6;
    const int lane = tid & 63;
    const int quad = lane >> 4;
    const int ln = lane & 15;
    const int lnx = ln & 7;
    const int hi3 = (ln >> 3) << 3;
    const int sc = (lane & 7) ^ (lane >> 3);

    __shared__ __align__(16) unsigned short Ks[2][64 * 64];   // 16 KB dbuf, swizzled
    __shared__ __align__(16) unsigned short Vs[2][64 * 64];   // 16 KB dbuf, swizzled [d][key]
    __shared__ __align__(16) unsigned short Ps[128 * 64];     // 16 KB, swizzled

    // Q A-fragments in registers for the whole kernel: 2 m-frags x 2 k-chunks
    short8 qa[2][2];
    #pragma unroll
    for (int m = 0; m < 2; m++) {
        const int qrow = q0 + wid * 32 + m * 16 + ln;
        qa[m][0] = *(const short8*)&Qb[(size_t)qrow * HD + h * DD + quad * 8];
        qa[m][1] = *(const short8*)&Qb[(size_t)qrow * HD + h * DD + 32 + quad * 8];
    }

    floatx4 O[2][4] = {};
    floatx4 S[2][4];
    float lsum[2][4] = {};

    // async staging: 16 B/lane, LDS slot j of row r <- source chunk j^(r&7)
    auto STAGE = [&](int kt, int bf) {
        const size_t k0 = (size_t)kt * 64;
        #pragma unroll
        for (int t = 0; t < 2; t++) {
            int row = wid * 16 + t * 8 + (lane >> 3);
            GLOAD_LDS(&Kb[(k0 + row) * HD + h * DD + sc * 8],
                      &Ks[bf][(wid * 16 + t * 8) * 64]);
            GLOAD_LDS(&VbT[(size_t)(h * DD + row) * NN + k0 + sc * 8],
                      &Vs[bf][(wid * 16 + t * 8) * 64]);
        }
    };

    // bias -> S registers (MFMA C-operand init). Rows: wid*32 + m*16 + quad*4 + r.
    const float* bbase = &bias[(size_t)(q0 + wid * 32 + quad * 4) * NN + ln];
    auto LBIAS_S = [&](int kt) {
        #pragma unroll
        for (int m = 0; m < 2; m++)
            #pragma unroll
            for (int n = 0; n < 4; n++)
                #pragma unroll
                for (int r = 0; r < 4; r++)
                    S[m][n][r] = bbase[(size_t)(m * 16 + r) * NN + kt * 64 + n * 16];
    };

    // prologue: stage tile tbeg + its bias; barrier waits the staging
    STAGE(tbeg, 0);
    LBIAS_S(tbeg);
    __syncthreads();

    #pragma unroll 1
    for (int kt = tbeg; kt < tend; ++kt) {
        const int bf = (kt - tbeg) & 1;
        const bool pre = (kt + 1 < tend);

        if (pre) STAGE(kt + 1, bf ^ 1);      // prefetch next tile (hidden below)

        // S = Q K^T + bias (bias preloaded into S as accumulator init)
        __builtin_amdgcn_s_setprio(1);
        #pragma unroll
        for (int n = 0; n < 4; n++) {
            short8 b0 = *(const short8*)&Ks[bf][(n * 16 + ln) * 64 + ((quad ^ lnx) * 8)];
            S[0][n] = __builtin_amdgcn_mfma_f32_16x16x32_bf16(qa[0][0], b0, S[0][n], 0, 0, 0);
            S[1][n] = __builtin_amdgcn_mfma_f32_16x16x32_bf16(qa[1][0], b0, S[1][n], 0, 0, 0);
            short8 b1 = *(const short8*)&Ks[bf][(n * 16 + ln) * 64 + (((quad ^ 4) ^ lnx) * 8)];
            S[0][n] = __builtin_amdgcn_mfma_f32_16x16x32_bf16(qa[0][1], b1, S[0][n], 0, 0, 0);
            S[1][n] = __builtin_amdgcn_mfma_f32_16x16x32_bf16(qa[1][1], b1, S[1][n], 0, 0, 0);
        }
        __builtin_amdgcn_s_setprio(0);

        // p = exp(S); fixed-max softmax (logits bounded), packed bf16 writes.
        // Ps position for col c=n*16+ln, row R: R*64 ^ (chunk^(R&7))<<3 ^ lnx
        #pragma unroll
        for (int m = 0; m < 2; m++) {
            #pragma unroll
            for (int r = 0; r < 4; r++) {
                int prow = wid * 32 + m * 16 + quad * 4 + r;
                int pb = (prow * 64 + lnx) ^ ((prow & 7) << 3) ^ hi3;
                #pragma unroll
                for (int n = 0; n < 4; n += 2) {
                    float p0 = __expf(S[m][n][r]);
                    float p1 = __expf(S[m][n + 1][r]);
                    lsum[m][r] += p0 + p1;
                    unsigned int pk = pack2bf(p0, p1);
                    Ps[pb ^ (n << 4)] = (unsigned short)(pk & 0xffffu);
                    Ps[pb ^ ((n + 1) << 4)] = (unsigned short)(pk >> 16);
                }
            }
        }
        // No barrier: Ps rows are wave-private.

        // bias for next tile -> S registers (S is dead; hides L2 latency under PV)
        if (pre) LBIAS_S(kt + 1);

        // O += P V
        __builtin_amdgcn_s_setprio(1);
        #pragma unroll
        for (int ks = 0; ks < 64; ks += 32) {
            const int cb = ks >> 3;
            short8 a0 = *(const short8*)&Ps[(wid * 32 + ln) * 64 +
                                            (((cb | quad) ^ lnx) * 8)];
            short8 a1 = *(const short8*)&Ps[(wid * 32 + 16 + ln) * 64 +
                                            (((cb | quad) ^ lnx) * 8)];
            #pragma unroll
            for (int nd = 0; nd < 4; nd++) {
                short8 vb = *(const short8*)&Vs[bf][(nd * 16 + ln) * 64 +
                                                    (((quad ^ cb) ^ lnx) * 8)];
                O[0][nd] = __builtin_amdgcn_mfma_f32_16x16x32_bf16(a0, vb, O[0][nd], 0, 0, 0);
                O[1][nd] = __builtin_amdgcn_mfma_f32_16x16x32_bf16(a1, vb, O[1][nd], 0, 0, 0);
            }
        }
        __builtin_amdgcn_s_setprio(0);

        if (pre)
            __syncthreads();   // vmcnt(0) drain == wait for prefetch; hidden by compute above
    }

    // epilogue: one 16-lane reduction for l; store O partial (bf16) + l
    #pragma unroll
    for (int m = 0; m < 2; m++) {
        #pragma unroll
        for (int r = 0; r < 4; r++) {
            #pragma unroll
            for (int off = 1; off < 16; off <<= 1)
                lsum[m][r] += __shfl_xor(lsum[m][r], off);
            int grow = q0 + wid * 32 + m * 16 + quad * 4 + r;
            size_t base = ((size_t)(sp * 8 + h) * NN + grow) * 64;
            #pragma unroll
            for (int nd = 0; nd < 4; nd++)
                Opart[base + nd * 16 + ln] = f2bf(O[m][nd][r]);
            if (ln == 0)
                Lpart[(size_t)(sp * 8 + h) * NN + grow] = lsum[m][r];
        }
    }
}

// ---------------------------------------------------------------------------
// Kernel 2b: combine split-K partials, normalize, gate -> OG bf16 [4096][512]
// ---------------------------------------------------------------------------
__global__ __launch_bounds__(256) void combine_kernel(
    const unsigned short* __restrict__ Opart, const float* __restrict__ Lpart,
    const unsigned short* __restrict__ Gb, unsigned short* __restrict__ OGb)
{
    const int tid = threadIdx.x;
    const int d = tid & 63;
    const int flat = blockIdx.x * 4 + (tid >> 6);   // [0, 8*4096)
    const int h = flat >> 12;
    const int q = flat & (NN - 1);

    float l = 0.0f, o = 0.0f;
    #pragma unroll
    for (int sp = 0; sp < KSPLIT; sp++) {
        size_t idx = (size_t)(sp * 8 + h) * NN + q;
        l += Lpart[idx];
        o += bf2f(Opart[idx * 64 + d]);
    }
    float inv = 1.0f / l;
    int col = h * DD + d;
    float g = bf2f(Gb[(size_t)q * HD + col]);
    OGb[(size_t)q * HD + col] = f2bf(o * inv * g);
}

// ---------------------------------------------------------------------------
// Kernel 3: out = OG[4096][512]bf16 @ wob^T([256][512]bf16) + bo -> fp32
// ---------------------------------------------------------------------------
__global__ __launch_bounds__(256, 4) void outproj_kernel(
    const unsigned short* __restrict__ OGb, const unsigned short* __restrict__ wob,
    const float* __restrict__ bo, float* __restrict__ out)
{
    const int m0 = blockIdx.x * 64;
    const int n0 = blockIdx.y * 64;
    const int tid = threadIdx.x;
    const int wid = tid >> 6;
    const int lane = tid & 63;
    const int quad = lane >> 4;
    const int ln = lane & 15;
    const int lnx = ln & 7;

    __shared__ __align__(16) unsigned short Xs[64 * 64];
    __shared__ __align__(16) unsigned short Ws[64 * 64];

    floatx4 acc[4] = {};

    for (int k0 = 0; k0 < HD; k0 += 64) {
        #pragma unroll
        for (int t = 0; t < 2; t++) {
            int row = wid * 16 + t * 8 + (lane >> 3);
            int c = (lane & 7) ^ (lane >> 3);
            GLOAD_LDS(&OGb[(size_t)(m0 + row) * HD + k0 + c * 8],
                      &Xs[(wid * 16 + t * 8) * 64]);
            GLOAD_LDS(&wob[(size_t)(n0 + row) * HD + k0 + c * 8],
                      &Ws[(wid * 16 + t * 8) * 64]);
        }
        __syncthreads();

        #pragma unroll
        for (int ks = 0; ks < 64; ks += 32) {
            const int cb = ks >> 3;
            short8 a = *(const short8*)&Xs[(wid * 16 + ln) * 64 +
                                           (((quad ^ cb) ^ lnx) * 8)];
            #pragma unroll
            for (int n = 0; n < 4; n++) {
                short8 b = *(const short8*)&Ws[(n * 16 + ln) * 64 +
                                               (((quad ^ cb) ^ lnx) * 8)];
                acc[n] = __builtin_amdgcn_mfma_f32_16x16x32_bf16(a, b, acc[n], 0, 0, 0);
            }
        }
        __syncthreads();
    }

    #pragma unroll
    for (int n = 0; n < 4; n++) {
        int col = n0 + n * 16 + ln;
        float bov = bo[col];
        #pragma unroll
        for (int r = 0; r < 4; r++) {
            int row = m0 + wid * 16 + quad * 4 + r;
            out[(size_t)row * CC + col] = acc[n][r] + bov;
        }
    }
}

// ---------------------------------------------------------------------------
extern "C" void kernel_launch(void* const* d_in, const int* in_sizes, int n_in,
                              void* d_out, int out_size, void* d_ws, size_t ws_size,
                              hipStream_t stream) {
    const float* qx   = (const float*)d_in[0];
    const float* kx   = (const float*)d_in[1];
    const float* vx   = (const float*)d_in[2];
    const float* bias = (const float*)d_in[3];
    const float* wq   = (const float*)d_in[4];
    const float* wk   = (const float*)d_in[5];
    const float* wv   = (const float*)d_in[6];
    const float* wg   = (const float*)d_in[7];
    const float* bg   = (const float*)d_in[8];
    const float* wo   = (const float*)d_in[9];
    const float* bo   = (const float*)d_in[10];
    float* out = (float*)d_out;

    // Workspace layout (peak ~34 MB). Opart overlays the prep buffers
    // qxb/kxb/vxb/Wb, which are dead once proj_kernel completes.
    char* ws = (char*)d_ws;
    const size_t MB = (size_t)1 << 20;
    unsigned short* wob   = (unsigned short*)(ws);                 // 0.25 MB
    float*          Lpart = (float*)(ws + MB / 4);                 // 0.4 MB
    unsigned short* Qb    = (unsigned short*)(ws + 1 * MB);        // 4 MB
    unsigned short* Kb    = (unsigned short*)(ws + 5 * MB);        // 4 MB
    unsigned short* VbT   = (unsigned short*)(ws + 9 * MB);        // 4 MB [512][4096]
    unsigned short* Gb    = (unsigned short*)(ws + 13 * MB);       // 4 MB
    unsigned short* OGb   = (unsigned short*)(ws + 17 * MB);       // 4 MB
    unsigned short* qxb   = (unsigned short*)(ws + 21 * MB);       // 2 MB (dead after proj)
    unsigned short* kxb   = (unsigned short*)(ws + 23 * MB);       // 2 MB (dead after proj)
    unsigned short* vxb   = (unsigned short*)(ws + 25 * MB);       // 2 MB (dead after proj)
    unsigned short* Wb    = (unsigned short*)(ws + 27 * MB);       // 1 MB (dead after proj)
    unsigned short* Opart = (unsigned short*)(ws + 21 * MB);       // 12.6 MB (overlays)

    prep_kernel<<<dim3(NN * CC / (256 * 4), 8), 256, 0, stream>>>(
        qx, kx, vx, wq, wk, wv, wg, wo, qxb, kxb, vxb, Wb, wob);
    proj_kernel<<<dim3(32, 16), 256, 0, stream>>>(
        qxb, kxb, vxb, Wb, bg, Qb, Kb, VbT, Gb);
    attn_kernel<<<dim3(32, 8, KSPLIT), 256, 0, stream>>>(
        Qb, Kb, VbT, bias, Opart, Lpart);
    combine_kernel<<<dim3(NN * 8 / 4), 256, 0, stream>>>(
        Opart, Lpart, Gb, OGb);
    outproj_kernel<<<dim3(64, 4), 256, 0, stream>>>(
        OGb, wob, bo, out);
}

// Round 3
// 235.586 us; speedup vs baseline: 1.0059x; 1.0059x over previous
//
#include <hip/hip_runtime.h>
#include <stdint.h>

// Problem constants: B=1, N=4096, C=256, H=8, D=64, H*D=512
#define NN 4096
#define CC 256
#define HD 512
#define DD 64
#define KSPLIT 3               // 64 k-tiles split 21/21/22 -> grid 1536 = 6 blocks/CU exactly

typedef __attribute__((ext_vector_type(8))) short short8;
typedef __attribute__((ext_vector_type(4))) short short4v;
typedef __attribute__((ext_vector_type(4))) float floatx4;

__device__ __forceinline__ unsigned short f2bf(float x) {
    union { float f; unsigned int u; } v; v.f = x;
    unsigned int u = v.u + 0x7fffu + ((v.u >> 16) & 1u);
    return (unsigned short)(u >> 16);
}
__device__ __forceinline__ float bf2f(unsigned short s) {
    union { unsigned int u; float f; } v; v.u = ((unsigned int)s) << 16;
    return v.f;
}

// Pack two f32 -> bf16x2 (lo = first arg), RNE. HW instr on gfx950.
#if defined(__has_builtin) && __has_builtin(__builtin_amdgcn_cvt_pk_bf16_f32)
typedef __attribute__((ext_vector_type(2))) __bf16 bf16x2_t;
__device__ __forceinline__ unsigned int pack2bf(float a, float b) {
    union { bf16x2_t v; unsigned int u; } x;
    x.v = __builtin_amdgcn_cvt_pk_bf16_f32(a, b);
    return x.u;
}
#else
__device__ __forceinline__ unsigned int pack2bf(float a, float b) {
    return ((unsigned int)f2bf(b) << 16) | (unsigned int)f2bf(a);
}
#endif

// 16x16x16 bf16 MFMA (A/B = 4 bf16 in 2 VGPRs). Builtin if present, else asm.
#if defined(__has_builtin) && __has_builtin(__builtin_amdgcn_mfma_f32_16x16x16bf16_1k)
__device__ __forceinline__ floatx4 mfma16(short4v a, short4v b, floatx4 c) {
    return __builtin_amdgcn_mfma_f32_16x16x16bf16_1k(a, b, c, 0, 0, 0);
}
#else
__device__ __forceinline__ floatx4 mfma16(short4v a, short4v b, floatx4 c) {
    asm("v_mfma_f32_16x16x16_bf16 %0, %1, %2, %0" : "+v"(c) : "v"(a), "v"(b));
    return c;
}
#endif

// Async global->LDS, 16 B per lane; LDS dest = wave-uniform base + lane*16.
#define GLOAD_LDS(gp, lp) __builtin_amdgcn_global_load_lds(                    \
    (__attribute__((address_space(1))) void*)(gp),                             \
    (__attribute__((address_space(3))) void*)(lp), 16, 0, 0)

// ---------------------------------------------------------------------------
// Kernel 0: fp32 -> bf16 prep. z selects region. wq pre-scaled by 0.125.
// ---------------------------------------------------------------------------
__global__ __launch_bounds__(256) void prep_kernel(
    const float* __restrict__ qx, const float* __restrict__ kx,
    const float* __restrict__ vx,
    const float* __restrict__ wq, const float* __restrict__ wk,
    const float* __restrict__ wv, const float* __restrict__ wg,
    const float* __restrict__ wo,
    unsigned short* __restrict__ qxb, unsigned short* __restrict__ kxb,
    unsigned short* __restrict__ vxb, unsigned short* __restrict__ Wb,
    unsigned short* __restrict__ wob)
{
    const int z = blockIdx.y;
    const float* src; unsigned short* dst; int n; float s = 1.0f;
    switch (z) {
        case 0: src = qx; dst = qxb; n = NN * CC; break;
        case 1: src = kx; dst = kxb; n = NN * CC; break;
        case 2: src = vx; dst = vxb; n = NN * CC; break;
        case 3: src = wq; dst = Wb;               n = HD * CC; s = 0.125f; break;
        case 4: src = wk; dst = Wb + 1 * HD * CC; n = HD * CC; break;
        case 5: src = wv; dst = Wb + 2 * HD * CC; n = HD * CC; break;
        case 6: src = wg; dst = Wb + 3 * HD * CC; n = HD * CC; break;
        default: src = wo; dst = wob;             n = CC * HD; break;
    }
    int i = (blockIdx.x * 256 + threadIdx.x) * 4;
    if (i < n) {
        float4 v = *(const float4*)&src[i];
        ushort4 p;
        p.x = f2bf(v.x * s); p.y = f2bf(v.y * s);
        p.z = f2bf(v.z * s); p.w = f2bf(v.w * s);
        *(ushort4*)&dst[i] = p;
    }
}

// ---------------------------------------------------------------------------
// Kernel 1: fused projection GEMM. X[4096][256]bf16 @ Wb[2048][256]^T.
// Tile 128x128, BK=64. Staging via global_load_lds (16B/lane) into UNPADDED
// rows (64 shorts = 128 B) with XOR chunk swizzle: LDS slot j of row r holds
// source 8-short chunk j^(r&7); reads XOR the same way -> conflict-free.
// ---------------------------------------------------------------------------
__global__ __launch_bounds__(256, 4) void proj_kernel(
    const unsigned short* __restrict__ qxb, const unsigned short* __restrict__ kxb,
    const unsigned short* __restrict__ vxb, const unsigned short* __restrict__ Wb,
    const float* __restrict__ bg,
    unsigned short* __restrict__ Qb, unsigned short* __restrict__ Kb,
    unsigned short* __restrict__ VbT, unsigned short* __restrict__ Gb)
{
    const int m0 = blockIdx.x * 128;
    const int nb = blockIdx.y;
    const int n0 = nb * 128;
    const int mode = nb >> 2;
    const unsigned short* X = (mode == 1) ? kxb : (mode == 2) ? vxb : qxb;

    const int tid = threadIdx.x;
    const int wid = tid >> 6;
    const int wr = wid >> 1, wc = wid & 1;
    const int lane = tid & 63;
    const int quad = lane >> 4;
    const int ln = lane & 15;
    const int lnx = ln & 7;

    // Xs: 128x64 @ smem[0], Ws: 128x64 @ smem[8192]; transpose scratch reuses
    // the whole buffer (128x136 = 17408 shorts) after the final barrier.
    __shared__ __align__(16) unsigned short smem[128 * 136];
    unsigned short* Xs = smem;
    unsigned short* Ws = smem + 128 * 64;

    floatx4 acc[4][4] = {};

    for (int k0 = 0; k0 < CC; k0 += 64) {
        #pragma unroll
        for (int t = 0; t < 4; t++) {
            int row = wid * 32 + t * 8 + (lane >> 3);
            int c = (lane & 7) ^ (lane >> 3);
            GLOAD_LDS(&X[(size_t)(m0 + row) * CC + k0 + c * 8],
                      &Xs[(wid * 32 + t * 8) * 64]);
            GLOAD_LDS(&Wb[(size_t)(n0 + row) * CC + k0 + c * 8],
                      &Ws[(wid * 32 + t * 8) * 64]);
        }
        __syncthreads();

        #pragma unroll
        for (int ks = 0; ks < 64; ks += 32) {
            const int cb = ks >> 3;    // 0 or 4
            short8 a[4], b[4];
            #pragma unroll
            for (int i = 0; i < 4; i++)
                a[i] = *(const short8*)&Xs[(wr * 64 + i * 16 + ln) * 64 +
                                           (((quad ^ cb) ^ lnx) * 8)];
            #pragma unroll
            for (int j = 0; j < 4; j++)
                b[j] = *(const short8*)&Ws[(wc * 64 + j * 16 + ln) * 64 +
                                           (((quad ^ cb) ^ lnx) * 8)];
            #pragma unroll
            for (int i = 0; i < 4; i++)
                #pragma unroll
                for (int j = 0; j < 4; j++)
                    acc[i][j] = __builtin_amdgcn_mfma_f32_16x16x32_bf16(a[i], b[j], acc[i][j], 0, 0, 0);
        }
        __syncthreads();
    }

    const int subn = nb & 3;
    if (mode != 2) {
        unsigned short* Out = (mode == 0) ? Qb : (mode == 1) ? Kb : Gb;
        #pragma unroll
        for (int i = 0; i < 4; i++) {
            #pragma unroll
            for (int j = 0; j < 4; j++) {
                int col = subn * 128 + wc * 64 + j * 16 + ln;
                float bgv = (mode == 3) ? bg[col] : 0.0f;
                #pragma unroll
                for (int r = 0; r < 4; r++) {
                    int row = m0 + wr * 64 + i * 16 + quad * 4 + r;
                    float v = acc[i][j][r];
                    if (mode == 3) v = 1.0f / (1.0f + __expf(-(v + bgv)));
                    Out[(size_t)row * HD + col] = f2bf(v);
                }
            }
        }
    } else {
        // V: transpose through smem, store coalesced to VbT[col][row]
        #pragma unroll
        for (int i = 0; i < 4; i++) {
            #pragma unroll
            for (int j = 0; j < 4; j++) {
                int cl = wc * 64 + j * 16 + ln;
                #pragma unroll
                for (int r = 0; r < 4; r++) {
                    int rl = wr * 64 + i * 16 + quad * 4 + r;
                    smem[cl * 136 + rl] = f2bf(acc[i][j][r]);
                }
            }
        }
        __syncthreads();
        #pragma unroll
        for (int it = 0; it < 8; it++) {
            int idx = it * 256 + tid;
            int c = idx >> 4, ch = idx & 15;
            short8 vv = *(const short8*)&smem[c * 136 + ch * 8];
            *(short8*)&VbT[(size_t)(subn * 128 + c) * NN + m0 + ch * 8] = vv;
        }
    }
}

// ---------------------------------------------------------------------------
// Kernel 2: flash attention, r0 shell (64 q-rows/block, single-buffered K/V,
// 6 blocks/CU, grid 1536) + swapped-operand QK^T: S^T = mfma(K,Q) puts
// P[q=ln][key=n*16+quad*4+r] lane-local, which IS the 16x16x16 A-fragment.
// P never touches LDS (8 cvt_pk in regs); PV = 16x mfma_16x16x16 with V read
// as ds_read_b64 (4 contiguous keys @ fixed d, b64 bank floor, conflict-free).
// Bias C-init becomes 4x float4 loads (r is contiguous in memory for S^T).
// LDS = Ks 8KB + Vs 8KB = 16 KB.
// ---------------------------------------------------------------------------
__global__ __launch_bounds__(256, 6) void attn_kernel(
    const unsigned short* __restrict__ Qb, const unsigned short* __restrict__ Kb,
    const unsigned short* __restrict__ VbT,
    const float* __restrict__ bias,
    unsigned short* __restrict__ Opart, float* __restrict__ Lpart)
{
    const int h = blockIdx.y;
    const int q0 = blockIdx.x * 64;
    const int sp = blockIdx.z;
    const int tbeg = (sp * 64) / KSPLIT;
    const int tend = ((sp + 1) * 64) / KSPLIT;
    const int tid = threadIdx.x;
    const int wid = tid >> 6;
    const int lane = tid & 63;
    const int quad = lane >> 4;
    const int ln = lane & 15;
    const int lnx = ln & 7;
    const int sc = (lane & 7) ^ (lane >> 3);

    __shared__ __align__(16) unsigned short Ks[64 * 64];   // 8 KB, swizzled
    __shared__ __align__(16) unsigned short Vs[64 * 64];   // 8 KB, swizzled [d][key]

    // Q fragments in registers for the whole kernel (B-operand of swapped QK;
    // identical register layout to the old A-operand).
    const int qrow = q0 + wid * 16 + ln;
    short8 qa0 = *(const short8*)&Qb[(size_t)qrow * HD + h * DD + quad * 8];
    short8 qa1 = *(const short8*)&Qb[(size_t)qrow * HD + h * DD + 32 + quad * 8];

    floatx4 O[4] = {};
    float lsum = 0.0f;

    // bias base for S^T C-init: lane (ln,quad) reg r = bias[q=qrow][k0+n*16+quad*4+r]
    const float* bbase = &bias[(size_t)qrow * NN + quad * 4];

    for (int kt = tbeg; kt < tend; kt++) {
        const int k0 = kt * 64;
        // async staging: 16 B/lane, LDS slot j of row r <- source chunk j^(r&7)
        #pragma unroll
        for (int t = 0; t < 2; t++) {
            int row = wid * 16 + t * 8 + (lane >> 3);
            GLOAD_LDS(&Kb[(size_t)(k0 + row) * HD + h * DD + sc * 8],
                      &Ks[(wid * 16 + t * 8) * 64]);
            GLOAD_LDS(&VbT[(size_t)(h * DD + row) * NN + k0 + sc * 8],
                      &Vs[(wid * 16 + t * 8) * 64]);
        }

        // bias -> S^T accumulator init (float4: r=0..3 contiguous)
        floatx4 S[4];
        #pragma unroll
        for (int n = 0; n < 4; n++) {
            float4 b4 = *(const float4*)&bbase[k0 + n * 16];
            S[n] = (floatx4){b4.x, b4.y, b4.z, b4.w};
        }
        __syncthreads();

        // S^T = K Q^T + bias : lane (ln,quad) reg r holds S[q=ln][n*16+quad*4+r]
        __builtin_amdgcn_s_setprio(1);
        #pragma unroll
        for (int n = 0; n < 4; n++) {
            short8 b0 = *(const short8*)&Ks[(n * 16 + ln) * 64 + ((quad ^ lnx) * 8)];
            S[n] = __builtin_amdgcn_mfma_f32_16x16x32_bf16(b0, qa0, S[n], 0, 0, 0);
            short8 b1 = *(const short8*)&Ks[(n * 16 + ln) * 64 + (((quad ^ 4) ^ lnx) * 8)];
            S[n] = __builtin_amdgcn_mfma_f32_16x16x32_bf16(b1, qa1, S[n], 0, 0, 0);
        }
        __builtin_amdgcn_s_setprio(0);

        // p = exp(S); fixed-max softmax (logits bounded). P stays in registers:
        // pa[n] = 16x16x16 A-fragment for key-block n. No LDS round-trip.
        short4v pa[4];
        #pragma unroll
        for (int n = 0; n < 4; n++) {
            float p0 = __expf(S[n][0]);
            float p1 = __expf(S[n][1]);
            float p2 = __expf(S[n][2]);
            float p3 = __expf(S[n][3]);
            lsum += (p0 + p1) + (p2 + p3);
            union { unsigned int u[2]; short4v s; } pk;
            pk.u[0] = pack2bf(p0, p1);
            pk.u[1] = pack2bf(p2, p3);
            pa[n] = pk.s;
        }

        // O += P V : per (n,nd) read 4 contiguous keys of row d (b64) as B-frag
        __builtin_amdgcn_s_setprio(1);
        #pragma unroll
        for (int n = 0; n < 4; n++) {
            #pragma unroll
            for (int nd = 0; nd < 4; nd++) {
                const int ch = (n * 2 + (quad >> 1)) ^ lnx;   // source chunk ^ row&7
                short4v vb = *(const short4v*)&Vs[(nd * 16 + ln) * 64 +
                                                  ch * 8 + (quad & 1) * 4];
                O[nd] = mfma16(pa[n], vb, O[nd]);
            }
        }
        __builtin_amdgcn_s_setprio(0);
        __syncthreads();
    }

    // epilogue: reduce lsum across quads (lane bits 4,5) -> row sum for q=ln
    lsum += __shfl_xor(lsum, 16);
    lsum += __shfl_xor(lsum, 32);

    #pragma unroll
    for (int r = 0; r < 4; r++) {
        int grow = q0 + wid * 16 + quad * 4 + r;
        size_t base = ((size_t)(sp * 8 + h) * NN + grow) * 64;
        #pragma unroll
        for (int nd = 0; nd < 4; nd++)
            Opart[base + nd * 16 + ln] = f2bf(O[nd][r]);
    }
    if (lane < 16)
        Lpart[(size_t)(sp * 8 + h) * NN + qrow] = lsum;
}

// ---------------------------------------------------------------------------
// Kernel 2b: combine split-K partials, normalize, gate -> OG bf16 [4096][512]
// ---------------------------------------------------------------------------
__global__ __launch_bounds__(256) void combine_kernel(
    const unsigned short* __restrict__ Opart, const float* __restrict__ Lpart,
    const unsigned short* __restrict__ Gb, unsigned short* __restrict__ OGb)
{
    const int tid = threadIdx.x;
    const int d = tid & 63;
    const int flat = blockIdx.x * 4 + (tid >> 6);   // [0, 8*4096)
    const int h = flat >> 12;
    const int q = flat & (NN - 1);

    float l = 0.0f, o = 0.0f;
    #pragma unroll
    for (int sp = 0; sp < KSPLIT; sp++) {
        size_t idx = (size_t)(sp * 8 + h) * NN + q;
        l += Lpart[idx];
        o += bf2f(Opart[idx * 64 + d]);
    }
    float inv = 1.0f / l;
    int col = h * DD + d;
    float g = bf2f(Gb[(size_t)q * HD + col]);
    OGb[(size_t)q * HD + col] = f2bf(o * inv * g);
}

// ---------------------------------------------------------------------------
// Kernel 3: out = OG[4096][512]bf16 @ wob^T([256][512]bf16) + bo -> fp32
// ---------------------------------------------------------------------------
__global__ __launch_bounds__(256, 4) void outproj_kernel(
    const unsigned short* __restrict__ OGb, const unsigned short* __restrict__ wob,
    const float* __restrict__ bo, float* __restrict__ out)
{
    const int m0 = blockIdx.x * 64;
    const int n0 = blockIdx.y * 64;
    const int tid = threadIdx.x;
    const int wid = tid >> 6;
    const int lane = tid & 63;
    const int quad = lane >> 4;
    const int ln = lane & 15;
    const int lnx = ln & 7;

    __shared__ __align__(16) unsigned short Xs[64 * 64];
    __shared__ __align__(16) unsigned short Ws[64 * 64];

    floatx4 acc[4] = {};

    for (int k0 = 0; k0 < HD; k0 += 64) {
        #pragma unroll
        for (int t = 0; t < 2; t++) {
            int row = wid * 16 + t * 8 + (lane >> 3);
            int c = (lane & 7) ^ (lane >> 3);
            GLOAD_LDS(&OGb[(size_t)(m0 + row) * HD + k0 + c * 8],
                      &Xs[(wid * 16 + t * 8) * 64]);
            GLOAD_LDS(&wob[(size_t)(n0 + row) * HD + k0 + c * 8],
                      &Ws[(wid * 16 + t * 8) * 64]);
        }
        __syncthreads();

        #pragma unroll
        for (int ks = 0; ks < 64; ks += 32) {
            const int cb = ks >> 3;
            short8 a = *(const short8*)&Xs[(wid * 16 + ln) * 64 +
                                           (((quad ^ cb) ^ lnx) * 8)];
            #pragma unroll
            for (int n = 0; n < 4; n++) {
                short8 b = *(const short8*)&Ws[(n * 16 + ln) * 64 +
                                               (((quad ^ cb) ^ lnx) * 8)];
                acc[n] = __builtin_amdgcn_mfma_f32_16x16x32_bf16(a, b, acc[n], 0, 0, 0);
            }
        }
        __syncthreads();
    }

    #pragma unroll
    for (int n = 0; n < 4; n++) {
        int col = n0 + n * 16 + ln;
        float bov = bo[col];
        #pragma unroll
        for (int r = 0; r < 4; r++) {
            int row = m0 + wid * 16 + quad * 4 + r;
            out[(size_t)row * CC + col] = acc[n][r] + bov;
        }
    }
}

// ---------------------------------------------------------------------------
extern "C" void kernel_launch(void* const* d_in, const int* in_sizes, int n_in,
                              void* d_out, int out_size, void* d_ws, size_t ws_size,
                              hipStream_t stream) {
    const float* qx   = (const float*)d_in[0];
    const float* kx   = (const float*)d_in[1];
    const float* vx   = (const float*)d_in[2];
    const float* bias = (const float*)d_in[3];
    const float* wq   = (const float*)d_in[4];
    const float* wk   = (const float*)d_in[5];
    const float* wv   = (const float*)d_in[6];
    const float* wg   = (const float*)d_in[7];
    const float* bg   = (const float*)d_in[8];
    const float* wo   = (const float*)d_in[9];
    const float* bo   = (const float*)d_in[10];
    float* out = (float*)d_out;

    // Workspace layout (peak ~34 MB). Opart overlays the prep buffers
    // qxb/kxb/vxb/Wb, which are dead once proj_kernel completes.
    char* ws = (char*)d_ws;
    const size_t MB = (size_t)1 << 20;
    unsigned short* wob   = (unsigned short*)(ws);                 // 0.25 MB
    float*          Lpart = (float*)(ws + MB / 4);                 // 0.4 MB
    unsigned short* Qb    = (unsigned short*)(ws + 1 * MB);        // 4 MB
    unsigned short* Kb    = (unsigned short*)(ws + 5 * MB);        // 4 MB
    unsigned short* VbT   = (unsigned short*)(ws + 9 * MB);        // 4 MB [512][4096]
    unsigned short* Gb    = (unsigned short*)(ws + 13 * MB);       // 4 MB
    unsigned short* OGb   = (unsigned short*)(ws + 17 * MB);       // 4 MB
    unsigned short* qxb   = (unsigned short*)(ws + 21 * MB);       // 2 MB (dead after proj)
    unsigned short* kxb   = (unsigned short*)(ws + 23 * MB);       // 2 MB (dead after proj)
    unsigned short* vxb   = (unsigned short*)(ws + 25 * MB);       // 2 MB (dead after proj)
    unsigned short* Wb    = (unsigned short*)(ws + 27 * MB);       // 1 MB (dead after proj)
    unsigned short* Opart = (unsigned short*)(ws + 21 * MB);       // 12.6 MB (overlays)

    prep_kernel<<<dim3(NN * CC / (256 * 4), 8), 256, 0, stream>>>(
        qx, kx, vx, wq, wk, wv, wg, wo, qxb, kxb, vxb, Wb, wob);
    proj_kernel<<<dim3(32, 16), 256, 0, stream>>>(
        qxb, kxb, vxb, Wb, bg, Qb, Kb, VbT, Gb);
    attn_kernel<<<dim3(64, 8, KSPLIT), 256, 0, stream>>>(
        Qb, Kb, VbT, bias, Opart, Lpart);
    combine_kernel<<<dim3(NN * 8 / 4), 256, 0, stream>>>(
        Opart, Lpart, Gb, OGb);
    outproj_kernel<<<dim3(64, 4), 256, 0, stream>>>(
        OGb, wob, bo, out);
}